// Round 3
// baseline (446.342 us; speedup 1.0000x reference)
//
#include <hip/hip_runtime.h>
#include <cstdint>

#define NPROP  48
#define MGRID  216
#define NPT    (NPROP*MGRID)      // 10368 points per batch
#define KPT    2048
#define CFEAT  128
#define R0SQ   0.64f              // 0.8^2 (f32-rounded same as reference)
#define R1SQ   2.56f              // 1.6^2
#define NS0    16
#define NS1    32
#define KRED   (CFEAT*MGRID)      // 27648
#define NPOINTS (2*NPT)           // 20736

// workspace layout (floats)
#define HID_SZ   (96*256)                   // 24576
#define Q0_OFF   24576
#define Q1_OFF   (Q0_OFF + 2*KPT*64)        // +262144
#define POOL_OFF (Q1_OFF + 2*KPT*64)        // +262144 ; poolT = [20736 pts][128 ch]
#define W0T_OFF  (POOL_OFF + NPOINTS*CFEAT) // +2654208 ; w0t = [256][27648] g-major
// total = 10,280,960 floats = 41.1 MB

// ---------------------------------------------------------------------------
// K1: w0t[o][g*128+c] = rw0[o][c*216+g]  (one-time weight transpose, 28 MB)
// ---------------------------------------------------------------------------
template <int W>
__device__ __forceinline__ void wtr_tile(const float* __restrict__ src,
                                         float* __restrict__ dst,
                                         float* __restrict__ t, int g0)
{
    const int stride = W + 1;
    for (int idx = threadIdx.x; idx < 128*W; idx += 256) {
        int c = idx / W, gg = idx - c*W;
        t[c*stride + gg] = src[c*216 + g0 + gg];     // coalesced along g
    }
    __syncthreads();
    for (int idx = threadIdx.x; idx < 128*W; idx += 256) {
        int gg = idx >> 7, c = idx & 127;
        dst[(size_t)(g0+gg)*128 + c] = t[c*stride + gg];  // coalesced along c
    }
    __syncthreads();
}

__global__ __launch_bounds__(256) void k_wtr(
    const float* __restrict__ rw0, float* __restrict__ ws)
{
    __shared__ float t[128*65];
    int o = blockIdx.x;
    const float* src = rw0 + (size_t)o*KRED;
    float* dst = ws + W0T_OFF + (size_t)o*KRED;
    wtr_tile<64>(src, dst, t, 0);
    wtr_tile<64>(src, dst, t, 64);
    wtr_tile<64>(src, dst, t, 128);
    wtr_tile<24>(src, dst, t, 192);
}

// ---------------------------------------------------------------------------
// K2: Q[s][b][k][o] = b0_s[o] + sum_i W_s[o][i]*kxyz[b][k][i]
//                            + sum_c W_s[o][3+c]*feats[b][c][k]
// ---------------------------------------------------------------------------
__global__ __launch_bounds__(256) void k_qproj(
    const float* __restrict__ kxyz, const float* __restrict__ feats,
    const float* __restrict__ w0, const float* __restrict__ b0,
    const float* __restrict__ w1, const float* __restrict__ b1,
    float* __restrict__ ws)
{
    __shared__ float wl[64*131];
    int bid  = blockIdx.x;
    int kgrp = bid & 511;
    int s    = (bid >> 9) & 1;
    int b    = bid >> 10;
    const float* W    = s ? w1 : w0;
    const float* bias = s ? b1 : b0;
    for (int i = threadIdx.x; i < 64*131; i += 256) wl[i] = W[i];
    __syncthreads();
    int k = kgrp*4 + (threadIdx.x >> 6);
    int o = threadIdx.x & 63;
    float acc = bias[o];
    const float* kp = kxyz + ((size_t)b*KPT + k)*3;
    acc = fmaf(wl[o*131+0], kp[0], acc);
    acc = fmaf(wl[o*131+1], kp[1], acc);
    acc = fmaf(wl[o*131+2], kp[2], acc);
    const float* f = feats + (size_t)b*CFEAT*KPT + k;
#pragma unroll 8
    for (int c = 0; c < CFEAT; ++c)
        acc = fmaf(wl[o*131+3+c], f[(size_t)c*KPT], acc);
    ws[Q0_OFF + (size_t)s*(2*KPT*64) + ((size_t)b*KPT + k)*64 + o] = acc;
}

// ---------------------------------------------------------------------------
// K3 main: one WAVE per (point, scale): ball query + MLP(Q[k]-u) + maxpool
// ---------------------------------------------------------------------------
__global__ __launch_bounds__(256, 4) void k_main(
    const float* __restrict__ proposals, const float* __restrict__ kxyz,
    const float* __restrict__ grid_noise,
    const float* __restrict__ w00, const float* __restrict__ w01,
    const float* __restrict__ b01,
    const float* __restrict__ w10, const float* __restrict__ w11,
    const float* __restrict__ b11,
    float* __restrict__ ws)
{
    __shared__ int idxs[4][32];
    __shared__ __align__(16) float hb[4][2][64];
    const int wid  = threadIdx.x >> 6;
    const int lane = threadIdx.x & 63;

    // scale-grouped task map: blocks [0,5184) = scale 0, [5184,10368) = scale 1
    const int s = (blockIdx.x >= 5184) ? 1 : 0;
    const int p = (blockIdx.x - s*5184)*4 + wid;   // < 20736
    int b   = p / NPT;
    int rem = p - b*NPT;
    int i   = rem / MGRID;
    int g   = rem - i*MGRID;

    const float* Wl1  = s ? w10 : w00;   // layer-1 (xyz columns)
    const float* Wl2  = s ? w11 : w01;   // layer-2 64x64
    const float* bs   = s ? b11 : b01;
    const float  rsq  = s ? R1SQ : R0SQ;
    const int    ns   = s ? NS1  : NS0;

    float ax = Wl1[lane*131+0], ay = Wl1[lane*131+1], az = Wl1[lane*131+2];

    const float* pr = proposals  + ((size_t)b*NPROP + i)*7;
    const float* gn = grid_noise + (((size_t)b*NPROP + i)*MGRID + g)*3;
    float gx = gn[0]*pr[3], gy = gn[1]*pr[4], gz = gn[2]*pr[5];
    float th = pr[6];
    float ss = sinf(th), cc = cosf(th);
    float nx = cc*gx - ss*gy + pr[0];
    float ny = ss*gx + cc*gy + pr[1];
    float nz = gz + pr[2];
    float pn2 = nx*nx + ny*ny + nz*nz;
    float u = ax*nx + ay*ny + az*nz;

    // ---- ball query: wave-parallel ordered-first-n selection ----
    int* idx = idxs[wid];
    int cnt = 0;
    const float* kb = kxyz + (size_t)b*KPT*3;
    unsigned long long ltm = (1ull << lane) - 1ull;
    for (int ck = 0; ck < KPT/64; ++ck) {
        int kk = ck*64 + lane;
        float kx = kb[kk*3+0], ky = kb[kk*3+1], kz = kb[kk*3+2];
        float kn2 = kx*kx + ky*ky + kz*kz;
        float dt  = nx*kx + ny*ky + nz*kz;
        float d2  = fmaf(-2.f, dt, pn2 + kn2);   // |p|^2+|k|^2-2p.k (ref form)
        unsigned long long m = __ballot(d2 < rsq);
        if (m) {
            int pre = __popcll(m & ltm);
            if (((m >> lane) & 1ull) && cnt + pre < ns) idx[cnt + pre] = kk;
            cnt += __popcll(m);
            if (cnt >= ns) break;                // wave-uniform
        }
    }
    if (lane == 0 && cnt == 0) idx[0] = 0;       // empty-ball fallback
    asm volatile("s_waitcnt lgkmcnt(0)" ::: "memory");
    __builtin_amdgcn_wave_barrier();
    int navail = cnt ? min(cnt, ns) : 1;

    // ---- load layer-2 weight row AFTER ball query (short live range, keep
    //      in 16 named float4s so the allocator doesn't push them to scratch)
    const float4* wr = (const float4*)(Wl2 + (size_t)lane*64);
    float4 wv0 = wr[0],  wv1 = wr[1],  wv2 = wr[2],  wv3 = wr[3];
    float4 wv4 = wr[4],  wv5 = wr[5],  wv6 = wr[6],  wv7 = wr[7];
    float4 wv8 = wr[8],  wv9 = wr[9],  wv10 = wr[10], wv11 = wr[11];
    float4 wv12 = wr[12], wv13 = wr[13], wv14 = wr[14], wv15 = wr[15];
    float bias = bs[lane];

    // ---- MLP + maxpool (clamped duplicate samples are max-neutral)
    const float* Qb = ws + Q0_OFF + (size_t)s*(2*KPT*64) + (size_t)b*(KPT*64);
    float* hb0 = hb[wid][0];
    float* hb1 = hb[wid][1];
    float mx = 0.f;
    int nm1 = navail - 1;

#define MLP_BODY(NSAMP)                                                       \
    {                                                                         \
        float qcur = Qb[((size_t)idx[0] << 6) + lane];                        \
        int t1 = (1 < nm1) ? 1 : nm1;                                         \
        float qn1 = Qb[((size_t)idx[t1] << 6) + lane];                        \
        _Pragma("unroll 4")                                                   \
        for (int t = 0; t < NSAMP; ++t) {                                     \
            int tn2 = t + 2; if (tn2 > nm1) tn2 = nm1;                        \
            float qn2 = Qb[((size_t)idx[tn2] << 6) + lane];                   \
            float h1 = fmaxf(qcur - u, 0.f);                                  \
            float* hw = (t & 1) ? hb1 : hb0;                                  \
            hw[lane] = h1;                                                    \
            __builtin_amdgcn_wave_barrier();                                  \
            const float4* hv = (const float4*)hw;                             \
            float a0 = bias, a1 = 0.f, a2 = 0.f, a3 = 0.f;                    \
            DOT(0,wv0)  DOT(1,wv1)  DOT(2,wv2)  DOT(3,wv3)                    \
            DOT(4,wv4)  DOT(5,wv5)  DOT(6,wv6)  DOT(7,wv7)                    \
            DOT(8,wv8)  DOT(9,wv9)  DOT(10,wv10) DOT(11,wv11)                 \
            DOT(12,wv12) DOT(13,wv13) DOT(14,wv14) DOT(15,wv15)               \
            __builtin_amdgcn_wave_barrier();                                  \
            float acc = (a0 + a1) + (a2 + a3);                                \
            mx = fmaxf(mx, fmaxf(acc, 0.f));                                  \
            qcur = qn1; qn1 = qn2;                                            \
        }                                                                     \
    }
#define DOT(J,W) { float4 h4 = hv[J];                                         \
        a0 = fmaf(W.x, h4.x, a0); a1 = fmaf(W.y, h4.y, a1);                   \
        a2 = fmaf(W.z, h4.z, a2); a3 = fmaf(W.w, h4.w, a3); }

    if (s == 0) MLP_BODY(NS0) else MLP_BODY(NS1)
#undef DOT
#undef MLP_BODY

    // coalesced pooled store: poolT[p][s*64+lane], 256 B contiguous per wave
    ws[POOL_OFF + (size_t)p*CFEAT + s*64 + lane] = mx;
}

// ---------------------------------------------------------------------------
// K4: hid[96][256] += A[96][27648] * B[256][27648]^T   (K-split, atomicAdd)
// A = poolT viewed as [96][216*128] (g-major), B = w0t (g-major) -> same dot
// grid = 216 ksplits x 2 o-tiles; block 256; per-thread 6r x 8o accumulators
// ---------------------------------------------------------------------------
__global__ __launch_bounds__(256) void k_red0(
    const float* __restrict__ A, const float* __restrict__ w0,
    float* __restrict__ hid)
{
    __shared__ __align__(16) float Al[96*68];
    __shared__ __align__(16) float Bl[128*68];
    int bid = blockIdx.x;
    int ot  = bid & 1;
    int ks  = bid >> 1;                      // 0..215
    int tid = threadIdx.x;
    int tx  = tid & 15, ty = tid >> 4;       // ty in [0,16): 6 rows each
    float acc[6][8] = {};

    for (int chunk = 0; chunk < 2; ++chunk) {
        int kk0 = ks*128 + chunk*64;
#pragma unroll
        for (int j = 0; j < 6; ++j) {        // stage A 96x64
            int f4 = tid + j*256;
            int rr = f4 >> 4, c4 = f4 & 15;
            float4 v = *(const float4*)(A + (size_t)rr*KRED + kk0 + c4*4);
            *(float4*)(Al + rr*68 + c4*4) = v;
        }
#pragma unroll
        for (int j = 0; j < 8; ++j) {        // stage B 128x64
            int f4 = tid + j*256;
            int rr = f4 >> 4, c4 = f4 & 15;
            float4 v = *(const float4*)(w0 + (size_t)(ot*128+rr)*KRED + kk0 + c4*4);
            *(float4*)(Bl + rr*68 + c4*4) = v;
        }
        __syncthreads();
#pragma unroll
        for (int k4 = 0; k4 < 16; ++k4) {
            float4 av[6], bv[8];
#pragma unroll
            for (int q = 0; q < 6; ++q) av[q] = *(const float4*)(Al + (ty*6+q)*68 + k4*4);
#pragma unroll
            for (int u = 0; u < 8; ++u) bv[u] = *(const float4*)(Bl + (u*16+tx)*68 + k4*4);
#pragma unroll
            for (int q = 0; q < 6; ++q)
#pragma unroll
                for (int u = 0; u < 8; ++u) {
                    acc[q][u] = fmaf(av[q].x, bv[u].x, acc[q][u]);
                    acc[q][u] = fmaf(av[q].y, bv[u].y, acc[q][u]);
                    acc[q][u] = fmaf(av[q].z, bv[u].z, acc[q][u]);
                    acc[q][u] = fmaf(av[q].w, bv[u].w, acc[q][u]);
                }
        }
        __syncthreads();
    }
#pragma unroll
    for (int q = 0; q < 6; ++q)
#pragma unroll
        for (int u = 0; u < 8; ++u)
            atomicAdd(hid + (size_t)(ty*6+q)*256 + ot*128 + u*16 + tx, acc[q][u]);
}

// ---------------------------------------------------------------------------
// K5: out = relu(relu(hid + b0) @ W1^T + b1)
// ---------------------------------------------------------------------------
__global__ __launch_bounds__(256) void k_fin(
    const float* __restrict__ hid, const float* __restrict__ rb0,
    const float* __restrict__ w1, const float* __restrict__ rb1,
    float* __restrict__ out)
{
    __shared__ __align__(16) float hbuf[256];
    int r = blockIdx.x, o = threadIdx.x;
    float h = fmaxf(hid[(size_t)r*256 + o] + rb0[o], 0.f);
    hbuf[o] = h;
    __syncthreads();
    float a0 = rb1[o], a1 = 0.f, a2 = 0.f, a3 = 0.f;
    const float4* wrow = (const float4*)(w1 + (size_t)o*256);
    const float4* hv   = (const float4*)hbuf;
#pragma unroll 8
    for (int j = 0; j < 64; ++j) {
        float4 w = wrow[j], x = hv[j];
        a0 = fmaf(w.x, x.x, a0);
        a1 = fmaf(w.y, x.y, a1);
        a2 = fmaf(w.z, x.z, a2);
        a3 = fmaf(w.w, x.w, a3);
    }
    out[(size_t)r*256 + o] = fmaxf((a0 + a1) + (a2 + a3), 0.f);
}

// ---------------------------------------------------------------------------
extern "C" void kernel_launch(void* const* d_in, const int* in_sizes, int n_in,
                              void* d_out, int out_size, void* d_ws, size_t ws_size,
                              hipStream_t stream)
{
    (void)in_sizes; (void)n_in; (void)out_size; (void)ws_size;
    const float* proposals = (const float*)d_in[0];
    const float* kxyz      = (const float*)d_in[1];
    const float* feats     = (const float*)d_in[2];
    const float* gnoise    = (const float*)d_in[3];
    const float* w0_0 = (const float*)d_in[4];
    const float* b0_0 = (const float*)d_in[5];
    const float* w0_1 = (const float*)d_in[6];
    const float* b0_1 = (const float*)d_in[7];
    const float* w1_0 = (const float*)d_in[8];
    const float* b1_0 = (const float*)d_in[9];
    const float* w1_1 = (const float*)d_in[10];
    const float* b1_1 = (const float*)d_in[11];
    const float* rw0  = (const float*)d_in[12];
    const float* rb0  = (const float*)d_in[13];
    const float* rw1  = (const float*)d_in[14];
    const float* rb1  = (const float*)d_in[15];
    float* ws  = (float*)d_ws;
    float* out = (float*)d_out;

    hipMemsetAsync(ws, 0, HID_SZ*sizeof(float), stream);                 // hid = 0
    k_wtr  <<< 256, 256, 0, stream>>>(rw0, ws);
    k_qproj<<<2048, 256, 0, stream>>>(kxyz, feats, w0_0, b0_0, w1_0, b1_0, ws);
    k_main <<<10368, 256, 0, stream>>>(proposals, kxyz, gnoise,
                                       w0_0, w0_1, b0_1, w1_0, w1_1, b1_1, ws);
    k_red0 <<< 432, 256, 0, stream>>>(ws + POOL_OFF, ws + W0T_OFF, ws);
    k_fin  <<<  96, 256, 0, stream>>>(ws, rb0, rw1, rb1, out);
}